// Round 8
// baseline (1321.921 us; speedup 1.0000x reference)
//
#include <hip/hip_runtime.h>
#include <hip/hip_bf16.h>
#include <math.h>

#define TTOK 8192
#define DM 1024
#define DFFN 4096
#define NEXP 4
#define CAPACITY 2560
#define EROWSN (2*CAPACITY)   // 5120 max rows per routed expert

typedef short bf16x8 __attribute__((ext_vector_type(8)));
typedef float f32x4 __attribute__((ext_vector_type(4)));

__device__ __forceinline__ unsigned short f2bf(float f) {
  unsigned int u = __float_as_uint(f);
  u = (u + 0x7fffu + ((u >> 16) & 1u)) >> 16;
  return (unsigned short)u;
}
__device__ __forceinline__ float bf2f(unsigned short h) {
  return __uint_as_float(((unsigned int)h) << 16);
}
// Abramowitz-Stegun 7.1.26 erf, |err| <= 1.5e-7
__device__ __forceinline__ float gelu_f(float v) {
  float z = fabsf(v) * 0.7071067811865476f;
  float t = 1.0f / (1.0f + 0.3275911f * z);
  float p = t * (0.254829592f +
            t * (-0.284496736f +
            t * (1.421413741f +
            t * (-1.453152027f + t * 1.061405429f))));
  float er = 1.0f - p * __expf(-z * z);
  er = v >= 0.f ? er : -er;
  return 0.5f * v * (1.0f + er);
}
__device__ __forceinline__ void gl16(const void* g, void* l) {
  __builtin_amdgcn_global_load_lds((const __attribute__((address_space(1))) void*)g,
                                   (__attribute__((address_space(3))) void*)l, 16, 0, 0);
}

// ---------------- convert x -> bf16 hi/lo, with zero pad row TTOK ----------------
__global__ void k_cvt_x(const float* __restrict__ x, unsigned short* __restrict__ xhi,
                        unsigned short* __restrict__ xlo) {
  int i = blockIdx.x * blockDim.x + threadIdx.x;
  const int n4 = (TTOK + 1) * DM / 4;
  if (i >= n4) return;
  int base = i * 4;
  float v[4] = {0.f, 0.f, 0.f, 0.f};
  if (base < TTOK * DM) {
    float4 f = *reinterpret_cast<const float4*>(x + base);
    v[0] = f.x; v[1] = f.y; v[2] = f.z; v[3] = f.w;
  }
  ushort4 h, l;
  unsigned short hh[4], ll[4];
#pragma unroll
  for (int j = 0; j < 4; j++) {
    hh[j] = f2bf(v[j]);
    ll[j] = f2bf(v[j] - bf2f(hh[j]));
  }
  h.x = hh[0]; h.y = hh[1]; h.z = hh[2]; h.w = hh[3];
  l.x = ll[0]; l.y = ll[1]; l.z = ll[2]; l.w = ll[3];
  reinterpret_cast<ushort4*>(xhi)[i] = h;
  reinterpret_cast<ushort4*>(xlo)[i] = l;
}

// ---- transpose + convert W[K][N] f32 -> Wt[N][K] bf16, full-line ushort8 writes ----
// grid (N/32, K/64), block (32,8)
__global__ void k_tcvt(const float* __restrict__ W, unsigned short* __restrict__ Wt,
                       int K, int N) {
  __shared__ float tile[64][33];
  int tx = threadIdx.x, ty = threadIdx.y;
  int n0 = blockIdx.x * 32, k0 = blockIdx.y * 64;
#pragma unroll
  for (int i = 0; i < 8; i++)
    tile[ty + i * 8][tx] = W[(size_t)(k0 + ty + i * 8) * N + n0 + tx];
  __syncthreads();
  int t = ty * 32 + tx;
  int n = t >> 3, ko = (t & 7) * 8;
  bf16x8 v;
#pragma unroll
  for (int i = 0; i < 8; i++) v[i] = (short)f2bf(tile[ko + i][n]);
  *reinterpret_cast<bf16x8*>(Wt + (size_t)(n0 + n) * K + k0 + ko) = v;
}

// transpose + convert to hi/lo pair (router weight), 32x32 (small, one use)
__global__ void k_tcvt2(const float* __restrict__ W, unsigned short* __restrict__ Whi,
                        unsigned short* __restrict__ Wlo, int K, int N) {
  __shared__ float tile[32][33];
  int tx = threadIdx.x, ty = threadIdx.y;
  int n0 = blockIdx.x * 32, k0 = blockIdx.y * 32;
#pragma unroll
  for (int i = 0; i < 4; i++)
    tile[ty + i * 8][tx] = W[(size_t)(k0 + ty + i * 8) * N + n0 + tx];
  __syncthreads();
#pragma unroll
  for (int i = 0; i < 4; i++) {
    float v = tile[tx][ty + i * 8];
    unsigned short h = f2bf(v);
    Whi[(size_t)(n0 + ty + i * 8) * K + k0 + tx] = h;
    Wlo[(size_t)(n0 + ty + i * 8) * K + k0 + tx] = f2bf(v - bf2f(h));
  }
}

// ---------------- router GEMM (128^2 2-phase, split-precision) ----------------
__global__ __launch_bounds__(256) void k_router(
    const unsigned short* __restrict__ xhi, const unsigned short* __restrict__ xlo,
    const unsigned short* __restrict__ whi, const unsigned short* __restrict__ wlo,
    const float* __restrict__ bias, float* __restrict__ Hr) {
  const int t = threadIdx.x;
  const int m0 = blockIdx.y * 128, n0 = blockIdx.x * 128;
  __shared__ unsigned short sAh[2][4096], sAl[2][4096], sBh[2][4096], sBl[2][4096];
  const int offA0 = t * 16, offA1 = offA0 + 4096;
  const int i0 = offA0 >> 1, i1 = offA1 >> 1;
  const int r0 = offA0 >> 6, c0e = (offA0 & 63) >> 1;
  const int r1 = offA1 >> 6, c1e = (offA1 & 63) >> 1;
  const unsigned short* pAh0 = xhi + (size_t)(m0 + r0) * DM + c0e;
  const unsigned short* pAh1 = xhi + (size_t)(m0 + r1) * DM + c1e;
  const unsigned short* pAl0 = xlo + (size_t)(m0 + r0) * DM + c0e;
  const unsigned short* pAl1 = xlo + (size_t)(m0 + r1) * DM + c1e;
  const unsigned short* pBh0 = whi + (size_t)(n0 + r0) * DM + c0e;
  const unsigned short* pBh1 = whi + (size_t)(n0 + r1) * DM + c1e;
  const unsigned short* pBl0 = wlo + (size_t)(n0 + r0) * DM + c0e;
  const unsigned short* pBl1 = wlo + (size_t)(n0 + r1) * DM + c1e;
  const int lane = t & 63, wid = t >> 6;
  const int wm = (wid >> 1) * 64, wn = (wid & 1) * 64;
  const int fr = lane & 15, fk = (lane >> 4) * 8;
  f32x4 acc[4][4];
#pragma unroll
  for (int m = 0; m < 4; m++)
#pragma unroll
    for (int n = 0; n < 4; n++) acc[m][n] = (f32x4){0.f, 0.f, 0.f, 0.f};

  auto stage = [&](int b, int k) {
    gl16(pAh0 + k, &sAh[b][i0]); gl16(pAh1 + k, &sAh[b][i1]);
    gl16(pAl0 + k, &sAl[b][i0]); gl16(pAl1 + k, &sAl[b][i1]);
    gl16(pBh0 + k, &sBh[b][i0]); gl16(pBh1 + k, &sBh[b][i1]);
    gl16(pBl0 + k, &sBl[b][i0]); gl16(pBl1 + k, &sBl[b][i1]);
  };

  int cur = 0;
  stage(0, 0);
  __syncthreads();
  for (int k0 = 0; k0 < DM; k0 += 32) {
    if (k0 + 32 < DM) stage(cur ^ 1, k0 + 32);
    bf16x8 ah[4], al[4], bh[4], bl[4];
#pragma unroll
    for (int m = 0; m < 4; m++) {
      ah[m] = *reinterpret_cast<const bf16x8*>(&sAh[cur][(wm + m * 16 + fr) * 32 + fk]);
      al[m] = *reinterpret_cast<const bf16x8*>(&sAl[cur][(wm + m * 16 + fr) * 32 + fk]);
    }
#pragma unroll
    for (int n = 0; n < 4; n++) {
      bh[n] = *reinterpret_cast<const bf16x8*>(&sBh[cur][(wn + n * 16 + fr) * 32 + fk]);
      bl[n] = *reinterpret_cast<const bf16x8*>(&sBl[cur][(wn + n * 16 + fr) * 32 + fk]);
    }
#pragma unroll
    for (int m = 0; m < 4; m++)
#pragma unroll
      for (int n = 0; n < 4; n++) {
        acc[m][n] = __builtin_amdgcn_mfma_f32_16x16x32_bf16(ah[m], bh[n], acc[m][n], 0, 0, 0);
        acc[m][n] = __builtin_amdgcn_mfma_f32_16x16x32_bf16(ah[m], bl[n], acc[m][n], 0, 0, 0);
        acc[m][n] = __builtin_amdgcn_mfma_f32_16x16x32_bf16(al[m], bh[n], acc[m][n], 0, 0, 0);
      }
    __syncthreads();
    cur ^= 1;
  }
  const int er = (lane >> 4) * 4, ec = lane & 15;
#pragma unroll
  for (int n = 0; n < 4; n++) {
    const int cc = n0 + wn + n * 16 + ec;
    const float bn = bias[cc];
#pragma unroll
    for (int m = 0; m < 4; m++) {
      const int rbase = m0 + wm + m * 16 + er;
#pragma unroll
      for (int j = 0; j < 4; j++)
        Hr[(size_t)(rbase + j) * DM + cc] = gelu_f(acc[m][n][j] + bn);
    }
  }
}

// ================= 256^2 GEMM, simple 2-phase (stage-next -> compute -> syncthreads) ======
// Strip mapping: A row = mh*128 + wr*64 + m*16 + fr ; B col = nh*128 + wc*32 + n*16 + fr.
// LDS: A [0,32768), B [32768,65536) shorts, each 2 bufs x [2 halves x 128 rows x 64 k].
// (row&7)<<4 byte-XOR swizzle on reads; staging uses inverse-swizzled global sources.
// MODE 0: FFN1 gathered rows -> gelu -> bf16 (early-exit rowsPad)
// MODE 1: FFN1 direct -> gelu -> bf16
// MODE 2: FFN2 routed, split-K z, atomic scatter w*(acc[+bias@z0]) (early-exit)
// MODE 3: FFN2 shared, split-K z, atomicAdd 0.5*(acc[+bias@z0])
// MODE 4: outproj, split-K z, atomicAdd (acc[+bias@z0]) into pre-zeroed OUTb
template <int MODE>
__global__ __launch_bounds__(512) void k_gemm256(
    const unsigned short* __restrict__ A, const unsigned short* __restrict__ Bt,
    const float* __restrict__ bias, float* __restrict__ outF,
    unsigned short* __restrict__ outBf, const int* __restrict__ rows,
    const float* __restrict__ rwgt, const int* __restrict__ rowsPad,
    int N, int K, int klen) {
  if constexpr (MODE == 0 || MODE == 2) {
    if ((int)(blockIdx.y * 256) >= rowsPad[0]) return;
  }
  __shared__ unsigned short lds[65536];  // 128 KB
  const int tid = threadIdx.x;
  const int lane = tid & 63, wid = tid >> 6;
  const int wr = wid >> 2, wc = wid & 3;
  const int fr = lane & 15;
  const int fkb = (lane >> 4) * 16;         // frag k-offset, bytes
  const int sw4 = (fr & 7) << 4;            // read-side swizzle XOR, bytes
  const int k0o = (fkb ^ sw4) >> 1;         // shorts (K elems 0..31)
  const int k1o = ((fkb + 64) ^ sw4) >> 1;  // shorts (K elems 32..63)
  const int m0 = blockIdx.y * 256, n0 = blockIdx.x * 256;
  int kbeg = 0;
  if constexpr (MODE >= 2) kbeg = blockIdx.z * klen;
  const int nt = klen >> 6;

  // stage sources: linear LDS dest, inverse-swizzled global src (same involution)
  const unsigned short *srcA[2][2], *srcB[2][2];
#pragma unroll
  for (int h = 0; h < 2; h++)
#pragma unroll
    for (int r = 0; r < 2; r++) {
      int d = h * 16384 + r * 8192 + tid * 16;   // byte offset within 32KB operand region
      int L = d ^ (((d >> 7) & 7) << 4);         // involution: byte ^= (row&7)<<4
      int row = L >> 7, k = (L & 127) >> 1;
      size_t arow;
      if constexpr (MODE == 0) arow = (size_t)rows[m0 + row];
      else arow = (size_t)(m0 + row);
      srcA[h][r] = A + arow * (size_t)K + kbeg + k;
      srcB[h][r] = Bt + (size_t)(n0 + row) * K + kbeg + k;
    }
  auto stA = [&](int buf, int h, int t) {
    unsigned short* d = lds + buf * 16384 + h * 8192 + tid * 8;
    gl16(srcA[h][0] + t * 64, d);
    gl16(srcA[h][1] + t * 64, d + 4096);
  };
  auto stB = [&](int buf, int h, int t) {
    unsigned short* d = lds + 32768 + buf * 16384 + h * 8192 + tid * 8;
    gl16(srcB[h][0] + t * 64, d);
    gl16(srcB[h][1] + t * 64, d + 4096);
  };

  f32x4 acc[8][4];
#pragma unroll
  for (int a = 0; a < 8; a++)
#pragma unroll
    for (int b = 0; b < 4; b++) acc[a][b] = (f32x4){0.f, 0.f, 0.f, 0.f};

  bf16x8 af0[4][2], af1[4][2], bf0[2][2], bf1[2][2];
  auto rdA = [&](bf16x8 (&dst)[4][2], int buf, int mh) {
    const unsigned short* Ab = lds + buf * 16384 + mh * 8192 + wr * 4096 + fr * 64;
#pragma unroll
    for (int m = 0; m < 4; m++) {
      dst[m][0] = *reinterpret_cast<const bf16x8*>(Ab + m * 1024 + k0o);
      dst[m][1] = *reinterpret_cast<const bf16x8*>(Ab + m * 1024 + k1o);
    }
  };
  auto rdB = [&](bf16x8 (&dst)[2][2], int buf, int nh) {
    const unsigned short* Bb = lds + 32768 + buf * 16384 + nh * 8192 + wc * 2048 + fr * 64;
#pragma unroll
    for (int n = 0; n < 2; n++) {
      dst[n][0] = *reinterpret_cast<const bf16x8*>(Bb + n * 1024 + k0o);
      dst[n][1] = *reinterpret_cast<const bf16x8*>(Bb + n * 1024 + k1o);
    }
  };

  // prologue: tile 0 into buf0
  stA(0, 0, 0); stA(0, 1, 0); stB(0, 0, 0); stB(0, 1, 0);
  __syncthreads();  // compiler emits vmcnt(0)+lgkmcnt(0) drain before barrier

  for (int s = 0; s < nt; ++s) {
    const int buf = s & 1;
    if (s + 1 < nt) {
      stA(buf ^ 1, 0, s + 1); stA(buf ^ 1, 1, s + 1);
      stB(buf ^ 1, 0, s + 1); stB(buf ^ 1, 1, s + 1);
    }
    rdA(af0, buf, 0); rdA(af1, buf, 1);
    rdB(bf0, buf, 0); rdB(bf1, buf, 1);
    // 64 MFMA, kk outer: same-acc updates are 32 apart (no dependent back-to-back)
#pragma unroll
    for (int kk = 0; kk < 2; kk++) {
#pragma unroll
      for (int m = 0; m < 4; m++) {
#pragma unroll
        for (int n = 0; n < 2; n++)
          acc[m][n] = __builtin_amdgcn_mfma_f32_16x16x32_bf16(af0[m][kk], bf0[n][kk], acc[m][n], 0, 0, 0);
#pragma unroll
        for (int n = 0; n < 2; n++)
          acc[m][2 + n] = __builtin_amdgcn_mfma_f32_16x16x32_bf16(af0[m][kk], bf1[n][kk], acc[m][2 + n], 0, 0, 0);
      }
#pragma unroll
      for (int m = 0; m < 4; m++) {
#pragma unroll
        for (int n = 0; n < 2; n++)
          acc[4 + m][n] = __builtin_amdgcn_mfma_f32_16x16x32_bf16(af1[m][kk], bf0[n][kk], acc[4 + m][n], 0, 0, 0);
#pragma unroll
        for (int n = 0; n < 2; n++)
          acc[4 + m][2 + n] = __builtin_amdgcn_mfma_f32_16x16x32_bf16(af1[m][kk], bf1[n][kk], acc[4 + m][2 + n], 0, 0, 0);
      }
    }
    __syncthreads();
  }

  // ---------------- epilogue ----------------
  const int er = (lane >> 4) * 4, ec = lane & 15;
  if constexpr (MODE <= 1) {
    // wave-private 16KB LDS chunk: rows 0..127 = mh*64+m*16+er+j, cols 0..63 = nh*32+n*16+ec
    unsigned short* cb = lds + wid * 8192;
#pragma unroll
    for (int b = 0; b < 4; b++) {
      const int nh = b >> 1, n = b & 1;
      const int cc = n0 + nh * 128 + wc * 32 + n * 16 + ec;
      const float bn = bias[cc];
      const int cl = nh * 32 + n * 16 + ec;
#pragma unroll
      for (int a = 0; a < 8; a++) {
        const int mh = a >> 2, m = a & 3;
#pragma unroll
        for (int j = 0; j < 4; j++) {
          int rl = mh * 64 + m * 16 + er + j;
          int addr = rl * 64 + ((((cl >> 3) ^ (rl & 7)) << 3) | (cl & 7));
          cb[addr] = f2bf(gelu_f(acc[a][b][j] + bn));
        }
      }
    }
#pragma unroll
    for (int it = 0; it < 16; it++) {
      int rl = it * 8 + (lane >> 3);
      int cblk = lane & 7;
      int laddr = rl * 64 + ((cblk ^ (rl & 7)) << 3);
      bf16x8 v = *reinterpret_cast<const bf16x8*>(cb + laddr);
      int grow = m0 + (rl >> 6) * 128 + wr * 64 + (rl & 63);
      int gcol = n0 + (cblk >> 2) * 128 + wc * 32 + (cblk & 3) * 8;
      *reinterpret_cast<bf16x8*>(outBf + (size_t)grow * N + gcol) = v;
    }
  } else {
    float bnz[4];
    int ccs[4];
#pragma unroll
    for (int b = 0; b < 4; b++) {
      ccs[b] = n0 + (b >> 1) * 128 + wc * 32 + (b & 1) * 16 + ec;
      bnz[b] = (blockIdx.z == 0) ? bias[ccs[b]] : 0.f;
    }
#pragma unroll
    for (int a = 0; a < 8; a++) {
#pragma unroll
      for (int j = 0; j < 4; j++) {
        const int rr = m0 + (a >> 2) * 128 + wr * 64 + (a & 3) * 16 + er + j;
        if constexpr (MODE == 2) {
          const int tok = rows[rr];
          if (tok < TTOK) {
            const float w = rwgt[rr];
#pragma unroll
            for (int b = 0; b < 4; b++)
              atomicAdd(outF + (size_t)tok * DM + ccs[b], w * (acc[a][b][j] + bnz[b]));
          }
        } else if constexpr (MODE == 3) {
#pragma unroll
          for (int b = 0; b < 4; b++)
            atomicAdd(outF + (size_t)rr * DM + ccs[b], 0.5f * (acc[a][b][j] + bnz[b]));
        } else {
#pragma unroll
          for (int b = 0; b < 4; b++)
            atomicAdd(outF + (size_t)rr * N + ccs[b], acc[a][b][j] + bnz[b]);
        }
      }
    }
  }
}

// ---------------- logits = Hr @ Rw2 + b2 (fp32 vector) ----------------
__global__ __launch_bounds__(256) void k_logits(const float* __restrict__ Hr,
                                                const float* __restrict__ w2,
                                                const float* __restrict__ b2,
                                                float* __restrict__ logits) {
  int tok = blockIdx.x * 4 + (threadIdx.x >> 6);
  int lane = threadIdx.x & 63;
  const float* h = Hr + (size_t)tok * DM;
  float s0 = 0.f, s1 = 0.f, s2 = 0.f, s3 = 0.f;
  for (int d = lane; d < DM; d += 64) {
    float hv = h[d];
    s0 += hv * w2[d * 4 + 0];
    s1 += hv * w2[d * 4 + 1];
    s2 += hv * w2[d * 4 + 2];
    s3 += hv * w2[d * 4 + 3];
  }
#pragma unroll
  for (int off = 32; off >= 1; off >>= 1) {
    s0 += __shfl_down(s0, off, 64);
    s1 += __shfl_down(s1, off, 64);
    s2 += __shfl_down(s2, off, 64);
    s3 += __shfl_down(s3, off, 64);
  }
  if (lane == 0) {
    logits[tok * 4 + 0] = s0 + b2[0];
    logits[tok * 4 + 1] = s1 + b2[1];
    logits[tok * 4 + 2] = s2 + b2[2];
    logits[tok * 4 + 3] = s3 + b2[3];
  }
}

// ---------------- top-2, softmax weights, z_loss ----------------
__global__ void k_topk(const float* __restrict__ logits, int* __restrict__ e0,
                       int* __restrict__ e1, float* __restrict__ w0,
                       float* __restrict__ w1, float* __restrict__ zout) {
  int tok = blockIdx.x * blockDim.x + threadIdx.x;
  if (tok >= TTOK) return;
  float l[4];
#pragma unroll
  for (int j = 0; j < 4; j++) l[j] = logits[tok * 4 + j];
  int i0 = 0; float v0 = l[0];
#pragma unroll
  for (int j = 1; j < 4; j++) if (l[j] > v0) { v0 = l[j]; i0 = j; }
  int i1 = -1; float v1 = -1e30f;
#pragma unroll
  for (int j = 0; j < 4; j++) if (j != i0 && l[j] > v1) { v1 = l[j]; i1 = j; }
  float d = expf(v1 - v0);
  float a = 1.f / (1.f + d);
  e0[tok] = i0; e1[tok] = i1;
  w0[tok] = a;  w1[tok] = d * a;
  float se = 0.f;
#pragma unroll
  for (int j = 0; j < 4; j++) se += expf(l[j] - v0);
  float lse = v0 + logf(se);
  atomicAdd(zout, lse * lse * (1.0f / TTOK));
}

// ---------------- per-(priority,expert) capacity lists, in token order ----------------
__global__ __launch_bounds__(256) void k_lists(const int* __restrict__ e0,
                                               const int* __restrict__ e1,
                                               const float* __restrict__ w0,
                                               const float* __restrict__ w1,
                                               int* __restrict__ list,
                                               float* __restrict__ lwgt,
                                               int* __restrict__ cnt) {
  int b = blockIdx.x;
  int prio = b >> 2, j = b & 3;
  const int* e = prio ? e1 : e0;
  const float* w = prio ? w1 : w0;
  __shared__ int warpsum[4];
  __shared__ int sbase;
  if (threadIdx.x == 0) sbase = 0;
  __syncthreads();
  int lane = threadIdx.x & 63, wv = threadIdx.x >> 6;
  for (int t0 = 0; t0 < TTOK; t0 += 256) {
    int tok = t0 + threadIdx.x;
    bool p = (e[tok] == j);
    unsigned long long bal = __ballot(p);
    int pre = __popcll(bal & ((1ull << lane) - 1ull));
    if (lane == 0) warpsum[wv] = __popcll(bal);
    __syncthreads();
    int woff = 0;
    for (int q = 0; q < wv; q++) woff += warpsum[q];
    int tot = warpsum[0] + warpsum[1] + warpsum[2] + warpsum[3];
    int slot = sbase + woff + pre;
    if (p && slot < CAPACITY) {
      list[b * CAPACITY + slot] = tok;
      lwgt[b * CAPACITY + slot] = w[tok];
    }
    __syncthreads();
    if (threadIdx.x == 0) sbase += tot;
    __syncthreads();
  }
  if (threadIdx.x == 0) cnt[b] = min(sbase, CAPACITY);
}

// ---------------- concatenate priorities per expert, pad with TTOK ----------------
__global__ void k_combine(const int* __restrict__ list, const float* __restrict__ lwgt,
                          const int* __restrict__ cnt, int* __restrict__ erows,
                          float* __restrict__ ewgt, int* __restrict__ rowsPad) {
  int j = blockIdx.x;
  int c0 = cnt[j], c1 = cnt[4 + j];
  for (int s = threadIdx.x; s < EROWSN; s += blockDim.x) {
    int tok = TTOK; float wv = 0.f;
    if (s < c0) { tok = list[j * CAPACITY + s]; wv = lwgt[j * CAPACITY + s]; }
    else if (s < c0 + c1) {
      tok = list[(4 + j) * CAPACITY + (s - c0)];
      wv = lwgt[(4 + j) * CAPACITY + (s - c0)];
    }
    erows[j * EROWSN + s] = tok;
    ewgt[j * EROWSN + s] = wv;
  }
  if (threadIdx.x == 0) rowsPad[j] = ((c0 + c1 + 255) / 256) * 256;
}

// ---------------- final f32 -> bf16 ----------------
__global__ void k_cvt_final(const float* __restrict__ f, unsigned short* __restrict__ fb) {
  int i = blockIdx.x * blockDim.x + threadIdx.x;
  if (i >= TTOK * DM / 4) return;
  float4 v = reinterpret_cast<const float4*>(f)[i];
  ushort4 o;
  o.x = f2bf(v.x); o.y = f2bf(v.y); o.z = f2bf(v.z); o.w = f2bf(v.w);
  reinterpret_cast<ushort4*>(fb)[i] = o;
}

// ---------------- residual blend + LayerNorm ----------------
__global__ __launch_bounds__(256) void k_ln(const float* __restrict__ OUT,
                                            const float* __restrict__ x,
                                            float* __restrict__ out) {
  int r = blockIdx.x;
  const float* o = OUT + (size_t)r * DM;
  const float* xr = x + (size_t)r * DM;
  int t = threadIdx.x;
  float v[4];
  float s = 0.f, s2 = 0.f;
#pragma unroll
  for (int i = 0; i < 4; i++) {
    int d = t + i * 256;
    float val = 0.5f * o[d] + 0.5f * xr[d];
    v[i] = val; s += val; s2 += val * val;
  }
#pragma unroll
  for (int off = 32; off >= 1; off >>= 1) {
    s += __shfl_down(s, off, 64);
    s2 += __shfl_down(s2, off, 64);
  }
  __shared__ float rs[4], rs2[4];
  int wv = t >> 6, lane = t & 63;
  if (lane == 0) { rs[wv] = s; rs2[wv] = s2; }
  __syncthreads();
  s = rs[0] + rs[1] + rs[2] + rs[3];
  s2 = rs2[0] + rs2[1] + rs2[2] + rs2[3];
  float mu = s * (1.f / DM);
  float var = s2 * (1.f / DM) - mu * mu;
  float inv = 1.0f / sqrtf(var + 1e-6f);
#pragma unroll
  for (int i = 0; i < 4; i++)
    out[(size_t)r * DM + t + i * 256] = (v[i] - mu) * inv;
}

// ---------------- workspace layout (total ~135 MB) ----------------
static constexpr size_t OFF_XHI = 0;
static constexpr size_t SZ_XHI = (size_t)(TTOK + 1) * DM * 2;
static constexpr size_t OFF_ACT = OFF_XHI + SZ_XHI;
static constexpr size_t SZ_ACT = (size_t)TTOK * DFFN * 2;
static constexpr size_t OFF_WBUF = OFF_ACT + SZ_ACT;
static constexpr size_t SZ_WBUF = (size_t)2 * DM * DFFN * 2;
static constexpr size_t OFF_FINAL = OFF_WBUF + SZ_WBUF;
static constexpr size_t SZ_FINAL = (size_t)TTOK * DM * 4;
static constexpr size_t OFF_MISC = OFF_FINAL + SZ_FINAL;
static constexpr size_t OFF_LOGITS = OFF_MISC;
static constexpr size_t OFF_E0 = OFF_LOGITS + (size_t)TTOK * 4 * 4;
static constexpr size_t OFF_E1 = OFF_E0 + (size_t)TTOK * 4;
static constexpr size_t OFF_W0 = OFF_E1 + (size_t)TTOK * 4;
static constexpr size_t OFF_W1 = OFF_W0 + (size_t)TTOK * 4;
static constexpr size_t OFF_LIST = OFF_W1 + (size_t)TTOK * 4;
static constexpr size_t OFF_LWGT = OFF_LIST + (size_t)8 * CAPACITY * 4;
static constexpr size_t OFF_CNT = OFF_LWGT + (size_t)8 * CAPACITY * 4;
static constexpr size_t OFF_EROWS = OFF_CNT + 64;
static constexpr size_t OFF_EWGT = OFF_EROWS + (size_t)NEXP * EROWSN * 4;
static constexpr size_t OFF_RPAD = OFF_EWGT + (size_t)NEXP * EROWSN * 4;

extern "C" void kernel_launch(void* const* d_in, const int* in_sizes, int n_in,
                              void* d_out, int out_size, void* d_ws, size_t ws_size,
                              hipStream_t stream) {
  const float* x = (const float*)d_in[0];
  const float* rw1 = (const float*)d_in[1];
  const float* rb1 = (const float*)d_in[2];
  const float* rw2 = (const float*)d_in[3];
  const float* rb2 = (const float*)d_in[4];
  const float* re_w1 = (const float*)d_in[5];
  const float* re_b1 = (const float*)d_in[6];
  const float* re_w2 = (const float*)d_in[7];
  const float* re_b2 = (const float*)d_in[8];
  const float* se_w1 = (const float*)d_in[9];
  const float* se_b1 = (const float*)d_in[10];
  const float* se_w2 = (const float*)d_in[11];
  const float* se_b2 = (const float*)d_in[12];
  const float* out_w = (const float*)d_in[13];
  const float* out_b = (const float*)d_in[14];
  float* outp = (float*)d_out;

  char* ws = (char*)d_ws;
  unsigned short* xhi = (unsigned short*)(ws + OFF_XHI);
  float* Hr = (float*)(ws + OFF_ACT);
  unsigned short* xlo = (unsigned short*)(ws + OFF_ACT + 33554432);
  unsigned short* act = (unsigned short*)(ws + OFF_ACT);
  unsigned short* fbf = (unsigned short*)(ws + OFF_ACT);
  float* OUTb = (float*)(ws + OFF_ACT + 16777216);
  unsigned short* w1t = (unsigned short*)(ws + OFF_WBUF);
  unsigned short* w2t = w1t + (size_t)DM * DFFN;
  unsigned short* rwhi = w1t;
  unsigned short* rwlo = w1t + (size_t)DM * DM;
  unsigned short* owt = w1t;
  float* finalb = (float*)(ws + OFF_FINAL);
  float* logits = (float*)(ws + OFF_LOGITS);
  int* e0 = (int*)(ws + OFF_E0);
  int* e1 = (int*)(ws + OFF_E1);
  float* w0 = (float*)(ws + OFF_W0);
  float* w1 = (float*)(ws + OFF_W1);
  int* list = (int*)(ws + OFF_LIST);
  float* lwgt = (float*)(ws + OFF_LWGT);
  int* cnt = (int*)(ws + OFF_CNT);
  int* erows = (int*)(ws + OFF_EROWS);
  float* ewgt = (float*)(ws + OFF_EWGT);
  int* rpad = (int*)(ws + OFF_RPAD);
  float* zout = outp + (size_t)TTOK * DM;

  hipMemsetAsync(finalb, 0, SZ_FINAL, stream);
  hipMemsetAsync(zout, 0, 4, stream);

  {
    int n4 = (TTOK + 1) * DM / 4;
    k_cvt_x<<<(n4 + 255) / 256, 256, 0, stream>>>(x, xhi, xlo);
  }
  // router
  k_tcvt2<<<dim3(DM / 32, DM / 32), dim3(32, 8), 0, stream>>>(rw1, rwhi, rwlo, DM, DM);
  k_router<<<dim3(DM / 128, TTOK / 128), 256, 0, stream>>>(xhi, xlo, rwhi, rwlo, rb1, Hr);
  k_logits<<<TTOK / 4, 256, 0, stream>>>(Hr, rw2, rb2, logits);
  k_topk<<<TTOK / 256, 256, 0, stream>>>(logits, e0, e1, w0, w1, zout);
  k_lists<<<8, 256, 0, stream>>>(e0, e1, w0, w1, list, lwgt, cnt);
  k_combine<<<NEXP, 256, 0, stream>>>(list, lwgt, cnt, erows, ewgt, rpad);

  // routed experts: FFN1 gather 256^2 -> act; FFN2 split-K=4 atomic scatter
  for (int j = 0; j < NEXP; j++) {
    k_tcvt<<<dim3(DFFN / 32, DM / 64), dim3(32, 8), 0, stream>>>(
        re_w1 + (size_t)j * DM * DFFN, w1t, DM, DFFN);
    k_tcvt<<<dim3(DM / 32, DFFN / 64), dim3(32, 8), 0, stream>>>(
        re_w2 + (size_t)j * DFFN * DM, w2t, DFFN, DM);
    k_gemm256<0><<<dim3(DFFN / 256, EROWSN / 256), 512, 0, stream>>>(
        xhi, w1t, re_b1 + (size_t)j * DFFN, nullptr, act,
        erows + (size_t)j * EROWSN, nullptr, rpad + j, DFFN, DM, DM);
    k_gemm256<2><<<dim3(DM / 256, EROWSN / 256, 4), 512, 0, stream>>>(
        act, w2t, re_b2 + (size_t)j * DM, finalb, nullptr,
        erows + (size_t)j * EROWSN, ewgt + (size_t)j * EROWSN, rpad + j, DM, DFFN, 1024);
  }
  // shared experts: FFN1 256^2; FFN2 split-K=2 atomic
  for (int j = 0; j < 2; j++) {
    k_tcvt<<<dim3(DFFN / 32, DM / 64), dim3(32, 8), 0, stream>>>(
        se_w1 + (size_t)j * DM * DFFN, w1t, DM, DFFN);
    k_tcvt<<<dim3(DM / 32, DFFN / 64), dim3(32, 8), 0, stream>>>(
        se_w2 + (size_t)j * DFFN * DM, w2t, DFFN, DM);
    k_gemm256<1><<<dim3(DFFN / 256, TTOK / 256), 512, 0, stream>>>(
        xhi, w1t, se_b1 + (size_t)j * DFFN, nullptr, act, nullptr, nullptr, nullptr,
        DFFN, DM, DM);
    k_gemm256<3><<<dim3(DM / 256, TTOK / 256, 2), 512, 0, stream>>>(
        act, w2t, se_b2 + (size_t)j * DM, finalb, nullptr, nullptr, nullptr, nullptr,
        DM, DFFN, 2048);
  }
  // output projection (split-K=2 atomic into zeroed OUTb) + LN
  k_cvt_final<<<TTOK * DM / 4 / 256, 256, 0, stream>>>(finalb, fbf);
  hipMemsetAsync(OUTb, 0, (size_t)TTOK * DM * 4, stream);
  k_tcvt<<<dim3(DM / 32, DM / 64), dim3(32, 8), 0, stream>>>(out_w, owt, DM, DM);
  k_gemm256<4><<<dim3(DM / 256, TTOK / 256, 2), 512, 0, stream>>>(
      fbf, owt, out_b, OUTb, nullptr, nullptr, nullptr, nullptr, DM, DM, 512);
  k_ln<<<TTOK, 256, 0, stream>>>(OUTb, x, outp);
}

// Round 9
// 1210.419 us; speedup vs baseline: 1.0921x; 1.0921x over previous
//
#include <hip/hip_runtime.h>
#include <hip/hip_bf16.h>
#include <math.h>

#define TTOK 8192
#define DM 1024
#define DFFN 4096
#define NEXP 4
#define CAPACITY 2560
#define EROWSN (2*CAPACITY)   // 5120 max rows per routed expert

typedef short bf16x8 __attribute__((ext_vector_type(8)));
typedef float f32x4 __attribute__((ext_vector_type(4)));

__device__ __forceinline__ unsigned short f2bf(float f) {
  unsigned int u = __float_as_uint(f);
  u = (u + 0x7fffu + ((u >> 16) & 1u)) >> 16;
  return (unsigned short)u;
}
__device__ __forceinline__ float bf2f(unsigned short h) {
  return __uint_as_float(((unsigned int)h) << 16);
}
// Abramowitz-Stegun 7.1.26 erf, |err| <= 1.5e-7
__device__ __forceinline__ float gelu_f(float v) {
  float z = fabsf(v) * 0.7071067811865476f;
  float t = 1.0f / (1.0f + 0.3275911f * z);
  float p = t * (0.254829592f +
            t * (-0.284496736f +
            t * (1.421413741f +
            t * (-1.453152027f + t * 1.061405429f))));
  float er = 1.0f - p * __expf(-z * z);
  er = v >= 0.f ? er : -er;
  return 0.5f * v * (1.0f + er);
}
__device__ __forceinline__ void gl16(const void* g, void* l) {
  __builtin_amdgcn_global_load_lds((const __attribute__((address_space(1))) void*)g,
                                   (__attribute__((address_space(3))) void*)l, 16, 0, 0);
}

// ---------------- convert x -> bf16 hi/lo, with zero pad row TTOK ----------------
__global__ void k_cvt_x(const float* __restrict__ x, unsigned short* __restrict__ xhi,
                        unsigned short* __restrict__ xlo) {
  int i = blockIdx.x * blockDim.x + threadIdx.x;
  const int n4 = (TTOK + 1) * DM / 4;
  if (i >= n4) return;
  int base = i * 4;
  float v[4] = {0.f, 0.f, 0.f, 0.f};
  if (base < TTOK * DM) {
    float4 f = *reinterpret_cast<const float4*>(x + base);
    v[0] = f.x; v[1] = f.y; v[2] = f.z; v[3] = f.w;
  }
  ushort4 h, l;
  unsigned short hh[4], ll[4];
#pragma unroll
  for (int j = 0; j < 4; j++) {
    hh[j] = f2bf(v[j]);
    ll[j] = f2bf(v[j] - bf2f(hh[j]));
  }
  h.x = hh[0]; h.y = hh[1]; h.z = hh[2]; h.w = hh[3];
  l.x = ll[0]; l.y = ll[1]; l.z = ll[2]; l.w = ll[3];
  reinterpret_cast<ushort4*>(xhi)[i] = h;
  reinterpret_cast<ushort4*>(xlo)[i] = l;
}

// ---- transpose + convert W[K][N] f32 -> Wt[N][K] bf16, full-line ushort8 writes ----
// grid (N/32, K/64), block (32,8)
__global__ void k_tcvt(const float* __restrict__ W, unsigned short* __restrict__ Wt,
                       int K, int N) {
  __shared__ float tile[64][33];
  int tx = threadIdx.x, ty = threadIdx.y;
  int n0 = blockIdx.x * 32, k0 = blockIdx.y * 64;
#pragma unroll
  for (int i = 0; i < 8; i++)
    tile[ty + i * 8][tx] = W[(size_t)(k0 + ty + i * 8) * N + n0 + tx];
  __syncthreads();
  int t = ty * 32 + tx;
  int n = t >> 3, ko = (t & 7) * 8;
  bf16x8 v;
#pragma unroll
  for (int i = 0; i < 8; i++) v[i] = (short)f2bf(tile[ko + i][n]);
  *reinterpret_cast<bf16x8*>(Wt + (size_t)(n0 + n) * K + k0 + ko) = v;
}

// transpose + convert to hi/lo pair (router weight)
__global__ void k_tcvt2(const float* __restrict__ W, unsigned short* __restrict__ Whi,
                        unsigned short* __restrict__ Wlo, int K, int N) {
  __shared__ float tile[32][33];
  int tx = threadIdx.x, ty = threadIdx.y;
  int n0 = blockIdx.x * 32, k0 = blockIdx.y * 32;
#pragma unroll
  for (int i = 0; i < 4; i++)
    tile[ty + i * 8][tx] = W[(size_t)(k0 + ty + i * 8) * N + n0 + tx];
  __syncthreads();
#pragma unroll
  for (int i = 0; i < 4; i++) {
    float v = tile[tx][ty + i * 8];
    unsigned short h = f2bf(v);
    Whi[(size_t)(n0 + ty + i * 8) * K + k0 + tx] = h;
    Wlo[(size_t)(n0 + ty + i * 8) * K + k0 + tx] = f2bf(v - bf2f(h));
  }
}

// ---------------- router GEMM (128^2 2-phase, split-precision) ----------------
__global__ __launch_bounds__(256) void k_router(
    const unsigned short* __restrict__ xhi, const unsigned short* __restrict__ xlo,
    const unsigned short* __restrict__ whi, const unsigned short* __restrict__ wlo,
    const float* __restrict__ bias, float* __restrict__ Hr) {
  const int t = threadIdx.x;
  const int m0 = blockIdx.y * 128, n0 = blockIdx.x * 128;
  __shared__ unsigned short sAh[2][4096], sAl[2][4096], sBh[2][4096], sBl[2][4096];
  const int offA0 = t * 16, offA1 = offA0 + 4096;
  const int i0 = offA0 >> 1, i1 = offA1 >> 1;
  const int r0 = offA0 >> 6, c0e = (offA0 & 63) >> 1;
  const int r1 = offA1 >> 6, c1e = (offA1 & 63) >> 1;
  const unsigned short* pAh0 = xhi + (size_t)(m0 + r0) * DM + c0e;
  const unsigned short* pAh1 = xhi + (size_t)(m0 + r1) * DM + c1e;
  const unsigned short* pAl0 = xlo + (size_t)(m0 + r0) * DM + c0e;
  const unsigned short* pAl1 = xlo + (size_t)(m0 + r1) * DM + c1e;
  const unsigned short* pBh0 = whi + (size_t)(n0 + r0) * DM + c0e;
  const unsigned short* pBh1 = whi + (size_t)(n0 + r1) * DM + c1e;
  const unsigned short* pBl0 = wlo + (size_t)(n0 + r0) * DM + c0e;
  const unsigned short* pBl1 = wlo + (size_t)(n0 + r1) * DM + c1e;
  const int lane = t & 63, wid = t >> 6;
  const int wm = (wid >> 1) * 64, wn = (wid & 1) * 64;
  const int fr = lane & 15, fk = (lane >> 4) * 8;
  f32x4 acc[4][4];
#pragma unroll
  for (int m = 0; m < 4; m++)
#pragma unroll
    for (int n = 0; n < 4; n++) acc[m][n] = (f32x4){0.f, 0.f, 0.f, 0.f};

  auto stage = [&](int b, int k) {
    gl16(pAh0 + k, &sAh[b][i0]); gl16(pAh1 + k, &sAh[b][i1]);
    gl16(pAl0 + k, &sAl[b][i0]); gl16(pAl1 + k, &sAl[b][i1]);
    gl16(pBh0 + k, &sBh[b][i0]); gl16(pBh1 + k, &sBh[b][i1]);
    gl16(pBl0 + k, &sBl[b][i0]); gl16(pBl1 + k, &sBl[b][i1]);
  };

  int cur = 0;
  stage(0, 0);
  __syncthreads();
  for (int k0 = 0; k0 < DM; k0 += 32) {
    if (k0 + 32 < DM) stage(cur ^ 1, k0 + 32);
    bf16x8 ah[4], al[4], bh[4], bl[4];
#pragma unroll
    for (int m = 0; m < 4; m++) {
      ah[m] = *reinterpret_cast<const bf16x8*>(&sAh[cur][(wm + m * 16 + fr) * 32 + fk]);
      al[m] = *reinterpret_cast<const bf16x8*>(&sAl[cur][(wm + m * 16 + fr) * 32 + fk]);
    }
#pragma unroll
    for (int n = 0; n < 4; n++) {
      bh[n] = *reinterpret_cast<const bf16x8*>(&sBh[cur][(wn + n * 16 + fr) * 32 + fk]);
      bl[n] = *reinterpret_cast<const bf16x8*>(&sBl[cur][(wn + n * 16 + fr) * 32 + fk]);
    }
#pragma unroll
    for (int m = 0; m < 4; m++)
#pragma unroll
      for (int n = 0; n < 4; n++) {
        acc[m][n] = __builtin_amdgcn_mfma_f32_16x16x32_bf16(ah[m], bh[n], acc[m][n], 0, 0, 0);
        acc[m][n] = __builtin_amdgcn_mfma_f32_16x16x32_bf16(ah[m], bl[n], acc[m][n], 0, 0, 0);
        acc[m][n] = __builtin_amdgcn_mfma_f32_16x16x32_bf16(al[m], bh[n], acc[m][n], 0, 0, 0);
      }
    __syncthreads();
    cur ^= 1;
  }
  const int er = (lane >> 4) * 4, ec = lane & 15;
#pragma unroll
  for (int n = 0; n < 4; n++) {
    const int cc = n0 + wn + n * 16 + ec;
    const float bn = bias[cc];
#pragma unroll
    for (int m = 0; m < 4; m++) {
      const int rbase = m0 + wm + m * 16 + er;
#pragma unroll
      for (int j = 0; j < 4; j++)
        Hr[(size_t)(rbase + j) * DM + cc] = gelu_f(acc[m][n][j] + bn);
    }
  }
}

// ---------------- main GEMM template, 128^2 2-phase (R3-proven) ----------------
// MODE 0: FFN1 gathered A (xhi via rows), gelu -> outBf (act), early-exit rowsPad
// MODE 1: FFN1 direct A, gelu -> outBf
// MODE 2: FFN2 routed, split-K=2 (blockIdx.z), atomicAdd w*(acc [+bias]) into outF, early-exit
// MODE 3: FFN2 shared: outF[r] += 0.5*(acc+bias)   (plain RMW, one owner per elem)
// MODE 4: outproj: outF[r*N+c] = acc + bias
template <int MODE>
__global__ __launch_bounds__(256) void k_gemm(
    const unsigned short* __restrict__ A, const unsigned short* __restrict__ Bt,
    const float* __restrict__ bias, float* __restrict__ outF,
    unsigned short* __restrict__ outBf, const int* __restrict__ rows,
    const float* __restrict__ rwgt, const int* __restrict__ rowsPad, int N, int K) {
  if constexpr (MODE == 0 || MODE == 2) {
    if ((int)(blockIdx.y * 128) >= rowsPad[0]) return;
  }
  const int t = threadIdx.x;
  const int m0 = blockIdx.y * 128, n0 = blockIdx.x * 128;
  int kbeg = 0, klen = K;
  if constexpr (MODE == 2) { kbeg = blockIdx.z * (K >> 1); klen = K >> 1; }
  // flat LDS: sA buffers at [0,8192) shorts, sB at [8192,16384); reused as C-staging
  __shared__ unsigned short smem[16384];
  const int offA0 = t * 16, offA1 = offA0 + 4096;
  const int i0 = offA0 >> 1, i1 = offA1 >> 1;
  const int r0 = offA0 >> 6, c0e = (offA0 & 63) >> 1;
  const int r1 = offA1 >> 6, c1e = (offA1 & 63) >> 1;
  size_t ar0 = m0 + r0, ar1 = m0 + r1;
  if constexpr (MODE == 0) { ar0 = rows[ar0]; ar1 = rows[ar1]; }
  const unsigned short* pA0 = A + ar0 * (size_t)K + kbeg + c0e;
  const unsigned short* pA1 = A + ar1 * (size_t)K + kbeg + c1e;
  const unsigned short* pB0 = Bt + (size_t)(n0 + r0) * K + kbeg + c0e;
  const unsigned short* pB1 = Bt + (size_t)(n0 + r1) * K + kbeg + c1e;
  const int lane = t & 63, wid = t >> 6;
  const int wm = (wid >> 1) * 64, wn = (wid & 1) * 64;
  const int fr = lane & 15, fk = (lane >> 4) * 8;
  f32x4 acc[4][4];
#pragma unroll
  for (int m = 0; m < 4; m++)
#pragma unroll
    for (int n = 0; n < 4; n++) acc[m][n] = (f32x4){0.f, 0.f, 0.f, 0.f};

  auto stage = [&](int b, int k) {
    gl16(pA0 + k, smem + b * 4096 + i0); gl16(pA1 + k, smem + b * 4096 + i1);
    gl16(pB0 + k, smem + 8192 + b * 4096 + i0); gl16(pB1 + k, smem + 8192 + b * 4096 + i1);
  };

  int cur = 0;
  stage(0, 0);
  __syncthreads();
  for (int k0 = 0; k0 < klen; k0 += 32) {
    if (k0 + 32 < klen) stage(cur ^ 1, k0 + 32);
    bf16x8 av[4], bv[4];
#pragma unroll
    for (int m = 0; m < 4; m++)
      av[m] = *reinterpret_cast<const bf16x8*>(smem + cur * 4096 + (wm + m * 16 + fr) * 32 + fk);
#pragma unroll
    for (int n = 0; n < 4; n++)
      bv[n] = *reinterpret_cast<const bf16x8*>(smem + 8192 + cur * 4096 + (wn + n * 16 + fr) * 32 + fk);
#pragma unroll
    for (int m = 0; m < 4; m++)
#pragma unroll
      for (int n = 0; n < 4; n++)
        acc[m][n] = __builtin_amdgcn_mfma_f32_16x16x32_bf16(av[m], bv[n], acc[m][n], 0, 0, 0);
    __syncthreads();
    cur ^= 1;
  }
  const int er = (lane >> 4) * 4, ec = lane & 15;
  if constexpr (MODE <= 1) {
    // LDS-staged coalesced bf16 epilogue: per-wave 64x64 tile (8KB chunk),
    // XOR-swizzled cols so the b128 re-reads are bank-conflict-free.
    unsigned short* cb = smem + wid * 4096;
#pragma unroll
    for (int n = 0; n < 4; n++) {
      const int cc = n0 + wn + n * 16 + ec;
      const float bn = bias[cc];
#pragma unroll
      for (int m = 0; m < 4; m++) {
#pragma unroll
        for (int j = 0; j < 4; j++) {
          int row = m * 16 + er + j;
          int col = n * 16 + ec;
          int addr = row * 64 + ((((col >> 3) ^ (row & 7)) << 3) | (col & 7));
          cb[addr] = f2bf(gelu_f(acc[m][n][j] + bn));
        }
      }
    }
    // same-wave ds_write -> ds_read: compiler inserts lgkmcnt wait; no barrier needed
#pragma unroll
    for (int it = 0; it < 8; it++) {
      int row = it * 8 + (lane >> 3);
      int cblk = lane & 7;
      int laddr = row * 64 + ((cblk ^ (row & 7)) << 3);
      bf16x8 v = *reinterpret_cast<const bf16x8*>(cb + laddr);
      *reinterpret_cast<bf16x8*>(outBf + (size_t)(m0 + wm + row) * N + (n0 + wn) + cblk * 8) = v;
    }
  } else {
#pragma unroll
    for (int n = 0; n < 4; n++) {
      const int cc = n0 + wn + n * 16 + ec;
      const float bn = bias[cc];
#pragma unroll
      for (int m = 0; m < 4; m++) {
        const int rbase = m0 + wm + m * 16 + er;
#pragma unroll
        for (int j = 0; j < 4; j++) {
          const int rr = rbase + j;
          if constexpr (MODE == 2) {
            float v = acc[m][n][j] + (blockIdx.z == 0 ? bn : 0.f);
            const int tok = rows[rr];
            if (tok < TTOK) atomicAdd(outF + (size_t)tok * DM + cc, rwgt[rr] * v);
          } else if constexpr (MODE == 3) {
            float* p = outF + (size_t)rr * DM + cc;
            *p += 0.5f * (acc[m][n][j] + bn);
          } else {
            outF[(size_t)rr * N + cc] = acc[m][n][j] + bn;
          }
        }
      }
    }
  }
}

// ---------------- logits = Hr @ Rw2 + b2 (fp32 vector) ----------------
__global__ __launch_bounds__(256) void k_logits(const float* __restrict__ Hr,
                                                const float* __restrict__ w2,
                                                const float* __restrict__ b2,
                                                float* __restrict__ logits) {
  int tok = blockIdx.x * 4 + (threadIdx.x >> 6);
  int lane = threadIdx.x & 63;
  const float* h = Hr + (size_t)tok * DM;
  float s0 = 0.f, s1 = 0.f, s2 = 0.f, s3 = 0.f;
  for (int d = lane; d < DM; d += 64) {
    float hv = h[d];
    s0 += hv * w2[d * 4 + 0];
    s1 += hv * w2[d * 4 + 1];
    s2 += hv * w2[d * 4 + 2];
    s3 += hv * w2[d * 4 + 3];
  }
#pragma unroll
  for (int off = 32; off >= 1; off >>= 1) {
    s0 += __shfl_down(s0, off, 64);
    s1 += __shfl_down(s1, off, 64);
    s2 += __shfl_down(s2, off, 64);
    s3 += __shfl_down(s3, off, 64);
  }
  if (lane == 0) {
    logits[tok * 4 + 0] = s0 + b2[0];
    logits[tok * 4 + 1] = s1 + b2[1];
    logits[tok * 4 + 2] = s2 + b2[2];
    logits[tok * 4 + 3] = s3 + b2[3];
  }
}

// ---------------- top-2, softmax weights, z_loss ----------------
__global__ void k_topk(const float* __restrict__ logits, int* __restrict__ e0,
                       int* __restrict__ e1, float* __restrict__ w0,
                       float* __restrict__ w1, float* __restrict__ zout) {
  int tok = blockIdx.x * blockDim.x + threadIdx.x;
  if (tok >= TTOK) return;
  float l[4];
#pragma unroll
  for (int j = 0; j < 4; j++) l[j] = logits[tok * 4 + j];
  int i0 = 0; float v0 = l[0];
#pragma unroll
  for (int j = 1; j < 4; j++) if (l[j] > v0) { v0 = l[j]; i0 = j; }
  int i1 = -1; float v1 = -1e30f;
#pragma unroll
  for (int j = 0; j < 4; j++) if (j != i0 && l[j] > v1) { v1 = l[j]; i1 = j; }
  float d = expf(v1 - v0);
  float a = 1.f / (1.f + d);
  e0[tok] = i0; e1[tok] = i1;
  w0[tok] = a;  w1[tok] = d * a;
  float se = 0.f;
#pragma unroll
  for (int j = 0; j < 4; j++) se += expf(l[j] - v0);
  float lse = v0 + logf(se);
  atomicAdd(zout, lse * lse * (1.0f / TTOK));
}

// ---------------- per-(priority,expert) capacity lists, in token order ----------------
__global__ __launch_bounds__(256) void k_lists(const int* __restrict__ e0,
                                               const int* __restrict__ e1,
                                               const float* __restrict__ w0,
                                               const float* __restrict__ w1,
                                               int* __restrict__ list,
                                               float* __restrict__ lwgt,
                                               int* __restrict__ cnt) {
  int b = blockIdx.x;
  int prio = b >> 2, j = b & 3;
  const int* e = prio ? e1 : e0;
  const float* w = prio ? w1 : w0;
  __shared__ int warpsum[4];
  __shared__ int sbase;
  if (threadIdx.x == 0) sbase = 0;
  __syncthreads();
  int lane = threadIdx.x & 63, wv = threadIdx.x >> 6;
  for (int t0 = 0; t0 < TTOK; t0 += 256) {
    int tok = t0 + threadIdx.x;
    bool p = (e[tok] == j);
    unsigned long long bal = __ballot(p);
    int pre = __popcll(bal & ((1ull << lane) - 1ull));
    if (lane == 0) warpsum[wv] = __popcll(bal);
    __syncthreads();
    int woff = 0;
    for (int q = 0; q < wv; q++) woff += warpsum[q];
    int tot = warpsum[0] + warpsum[1] + warpsum[2] + warpsum[3];
    int slot = sbase + woff + pre;
    if (p && slot < CAPACITY) {
      list[b * CAPACITY + slot] = tok;
      lwgt[b * CAPACITY + slot] = w[tok];
    }
    __syncthreads();
    if (threadIdx.x == 0) sbase += tot;
    __syncthreads();
  }
  if (threadIdx.x == 0) cnt[b] = min(sbase, CAPACITY);
}

// ---------------- concatenate priorities per expert, pad with TTOK ----------------
__global__ void k_combine(const int* __restrict__ list, const float* __restrict__ lwgt,
                          const int* __restrict__ cnt, int* __restrict__ erows,
                          float* __restrict__ ewgt, int* __restrict__ rowsPad) {
  int j = blockIdx.x;
  int c0 = cnt[j], c1 = cnt[4 + j];
  for (int s = threadIdx.x; s < EROWSN; s += blockDim.x) {
    int tok = TTOK; float wv = 0.f;
    if (s < c0) { tok = list[j * CAPACITY + s]; wv = lwgt[j * CAPACITY + s]; }
    else if (s < c0 + c1) {
      tok = list[(4 + j) * CAPACITY + (s - c0)];
      wv = lwgt[(4 + j) * CAPACITY + (s - c0)];
    }
    erows[j * EROWSN + s] = tok;
    ewgt[j * EROWSN + s] = wv;
  }
  if (threadIdx.x == 0) rowsPad[j] = ((c0 + c1 + 127) / 128) * 128;
}

// ---------------- final f32 -> bf16 ----------------
__global__ void k_cvt_final(const float* __restrict__ f, unsigned short* __restrict__ fb) {
  int i = blockIdx.x * blockDim.x + threadIdx.x;
  if (i >= TTOK * DM / 4) return;
  float4 v = reinterpret_cast<const float4*>(f)[i];
  ushort4 o;
  o.x = f2bf(v.x); o.y = f2bf(v.y); o.z = f2bf(v.z); o.w = f2bf(v.w);
  reinterpret_cast<ushort4*>(fb)[i] = o;
}

// ---------------- residual blend + LayerNorm ----------------
__global__ __launch_bounds__(256) void k_ln(const float* __restrict__ OUT,
                                            const float* __restrict__ x,
                                            float* __restrict__ out) {
  int r = blockIdx.x;
  const float* o = OUT + (size_t)r * DM;
  const float* xr = x + (size_t)r * DM;
  int t = threadIdx.x;
  float v[4];
  float s = 0.f, s2 = 0.f;
#pragma unroll
  for (int i = 0; i < 4; i++) {
    int d = t + i * 256;
    float val = 0.5f * o[d] + 0.5f * xr[d];
    v[i] = val; s += val; s2 += val * val;
  }
#pragma unroll
  for (int off = 32; off >= 1; off >>= 1) {
    s += __shfl_down(s, off, 64);
    s2 += __shfl_down(s2, off, 64);
  }
  __shared__ float rs[4], rs2[4];
  int wv = t >> 6, lane = t & 63;
  if (lane == 0) { rs[wv] = s; rs2[wv] = s2; }
  __syncthreads();
  s = rs[0] + rs[1] + rs[2] + rs[3];
  s2 = rs2[0] + rs2[1] + rs2[2] + rs2[3];
  float mu = s * (1.f / DM);
  float var = s2 * (1.f / DM) - mu * mu;
  float inv = 1.0f / sqrtf(var + 1e-6f);
#pragma unroll
  for (int i = 0; i < 4; i++)
    out[(size_t)r * DM + t + i * 256] = (v[i] - mu) * inv;
}

// ---------------- workspace layout (total ~135 MB) ----------------
static constexpr size_t OFF_XHI = 0;
static constexpr size_t SZ_XHI = (size_t)(TTOK + 1) * DM * 2;
static constexpr size_t OFF_ACT = OFF_XHI + SZ_XHI;
static constexpr size_t SZ_ACT = (size_t)TTOK * DFFN * 2;
static constexpr size_t OFF_WBUF = OFF_ACT + SZ_ACT;
static constexpr size_t SZ_WBUF = (size_t)2 * DM * DFFN * 2;
static constexpr size_t OFF_FINAL = OFF_WBUF + SZ_WBUF;
static constexpr size_t SZ_FINAL = (size_t)TTOK * DM * 4;
static constexpr size_t OFF_MISC = OFF_FINAL + SZ_FINAL;
static constexpr size_t OFF_LOGITS = OFF_MISC;
static constexpr size_t OFF_E0 = OFF_LOGITS + (size_t)TTOK * 4 * 4;
static constexpr size_t OFF_E1 = OFF_E0 + (size_t)TTOK * 4;
static constexpr size_t OFF_W0 = OFF_E1 + (size_t)TTOK * 4;
static constexpr size_t OFF_W1 = OFF_W0 + (size_t)TTOK * 4;
static constexpr size_t OFF_LIST = OFF_W1 + (size_t)TTOK * 4;
static constexpr size_t OFF_LWGT = OFF_LIST + (size_t)8 * CAPACITY * 4;
static constexpr size_t OFF_CNT = OFF_LWGT + (size_t)8 * CAPACITY * 4;
static constexpr size_t OFF_EROWS = OFF_CNT + 64;
static constexpr size_t OFF_EWGT = OFF_EROWS + (size_t)NEXP * EROWSN * 4;
static constexpr size_t OFF_RPAD = OFF_EWGT + (size_t)NEXP * EROWSN * 4;

extern "C" void kernel_launch(void* const* d_in, const int* in_sizes, int n_in,
                              void* d_out, int out_size, void* d_ws, size_t ws_size,
                              hipStream_t stream) {
  const float* x = (const float*)d_in[0];
  const float* rw1 = (const float*)d_in[1];
  const float* rb1 = (const float*)d_in[2];
  const float* rw2 = (const float*)d_in[3];
  const float* rb2 = (const float*)d_in[4];
  const float* re_w1 = (const float*)d_in[5];
  const float* re_b1 = (const float*)d_in[6];
  const float* re_w2 = (const float*)d_in[7];
  const float* re_b2 = (const float*)d_in[8];
  const float* se_w1 = (const float*)d_in[9];
  const float* se_b1 = (const float*)d_in[10];
  const float* se_w2 = (const float*)d_in[11];
  const float* se_b2 = (const float*)d_in[12];
  const float* out_w = (const float*)d_in[13];
  const float* out_b = (const float*)d_in[14];
  float* outp = (float*)d_out;

  char* ws = (char*)d_ws;
  unsigned short* xhi = (unsigned short*)(ws + OFF_XHI);
  float* Hr = (float*)(ws + OFF_ACT);
  unsigned short* xlo = (unsigned short*)(ws + OFF_ACT + 33554432);
  unsigned short* act = (unsigned short*)(ws + OFF_ACT);
  unsigned short* fbf = (unsigned short*)(ws + OFF_ACT);
  float* OUTb = (float*)(ws + OFF_ACT + 16777216);
  unsigned short* w1t = (unsigned short*)(ws + OFF_WBUF);
  unsigned short* w2t = w1t + (size_t)DM * DFFN;
  unsigned short* rwhi = w1t;
  unsigned short* rwlo = w1t + (size_t)DM * DM;
  unsigned short* owt = w1t;
  float* finalb = (float*)(ws + OFF_FINAL);
  float* logits = (float*)(ws + OFF_LOGITS);
  int* e0 = (int*)(ws + OFF_E0);
  int* e1 = (int*)(ws + OFF_E1);
  float* w0 = (float*)(ws + OFF_W0);
  float* w1 = (float*)(ws + OFF_W1);
  int* list = (int*)(ws + OFF_LIST);
  float* lwgt = (float*)(ws + OFF_LWGT);
  int* cnt = (int*)(ws + OFF_CNT);
  int* erows = (int*)(ws + OFF_EROWS);
  float* ewgt = (float*)(ws + OFF_EWGT);
  int* rpad = (int*)(ws + OFF_RPAD);
  float* zout = outp + (size_t)TTOK * DM;

  hipMemsetAsync(finalb, 0, SZ_FINAL, stream);
  hipMemsetAsync(zout, 0, 4, stream);

  {
    int n4 = (TTOK + 1) * DM / 4;
    k_cvt_x<<<(n4 + 255) / 256, 256, 0, stream>>>(x, xhi, xlo);
  }
  // router
  k_tcvt2<<<dim3(DM / 32, DM / 32), dim3(32, 8), 0, stream>>>(rw1, rwhi, rwlo, DM, DM);
  k_router<<<dim3(DM / 128, TTOK / 128), 256, 0, stream>>>(xhi, xlo, rwhi, rwlo, rb1, Hr);
  k_logits<<<TTOK / 4, 256, 0, stream>>>(Hr, rw2, rb2, logits);
  k_topk<<<TTOK / 256, 256, 0, stream>>>(logits, e0, e1, w0, w1, zout);
  k_lists<<<8, 256, 0, stream>>>(e0, e1, w0, w1, list, lwgt, cnt);
  k_combine<<<NEXP, 256, 0, stream>>>(list, lwgt, cnt, erows, ewgt, rpad);

  // routed experts: FFN1 (gather) -> act, FFN2 split-K=2 scatter-atomic -> finalb
  for (int j = 0; j < NEXP; j++) {
    k_tcvt<<<dim3(DFFN / 32, DM / 64), dim3(32, 8), 0, stream>>>(
        re_w1 + (size_t)j * DM * DFFN, w1t, DM, DFFN);
    k_tcvt<<<dim3(DM / 32, DFFN / 64), dim3(32, 8), 0, stream>>>(
        re_w2 + (size_t)j * DFFN * DM, w2t, DFFN, DM);
    k_gemm<0><<<dim3(DFFN / 128, EROWSN / 128), 256, 0, stream>>>(
        xhi, w1t, re_b1 + (size_t)j * DFFN, nullptr, act,
        erows + (size_t)j * EROWSN, nullptr, rpad + j, DFFN, DM);
    k_gemm<2><<<dim3(DM / 128, EROWSN / 128, 2), 256, 0, stream>>>(
        act, w2t, re_b2 + (size_t)j * DM, finalb, nullptr,
        erows + (size_t)j * EROWSN, ewgt + (size_t)j * EROWSN, rpad + j, DM, DFFN);
  }
  // shared experts: FFN1 -> act, FFN2 plain RMW += 0.5*(.) into finalb
  for (int j = 0; j < 2; j++) {
    k_tcvt<<<dim3(DFFN / 32, DM / 64), dim3(32, 8), 0, stream>>>(
        se_w1 + (size_t)j * DM * DFFN, w1t, DM, DFFN);
    k_tcvt<<<dim3(DM / 32, DFFN / 64), dim3(32, 8), 0, stream>>>(
        se_w2 + (size_t)j * DFFN * DM, w2t, DFFN, DM);
    k_gemm<1><<<dim3(DFFN / 128, TTOK / 128), 256, 0, stream>>>(
        xhi, w1t, se_b1 + (size_t)j * DFFN, nullptr, act, nullptr, nullptr, nullptr,
        DFFN, DM);
    k_gemm<3><<<dim3(DM / 128, TTOK / 128), 256, 0, stream>>>(
        act, w2t, se_b2 + (size_t)j * DM, finalb, nullptr, nullptr, nullptr, nullptr,
        DM, DFFN);
  }
  // output projection + LN
  k_cvt_final<<<TTOK * DM / 4 / 256, 256, 0, stream>>>(finalb, fbf);
  k_tcvt<<<dim3(DM / 32, DM / 64), dim3(32, 8), 0, stream>>>(out_w, owt, DM, DM);
  k_gemm<4><<<dim3(DM / 128, TTOK / 128), 256, 0, stream>>>(
      fbf, owt, out_b, OUTb, nullptr, nullptr, nullptr, nullptr, DM, DM);
  k_ln<<<TTOK, 256, 0, stream>>>(OUTb, x, outp);
}